// Round 2
// baseline (61.912 us; speedup 1.0000x reference)
//
#include <hip/hip_runtime.h>
#include <hip/hip_bf16.h>

// Decorrelation forward:
// out[n,j] = x[n,j] + sum_{i<j} sum_k Bin(9,k)*u_i^k*(1-u_i)^(9-k) * P[k,(i,j)] * x[n,i]
// u_i = (x[n,i] - lo_i) / (hi_i - lo_i)
//
// Weights repacked by prep kernel into d_ws, then D2D-copied into __constant__
// cW so the main kernel's coefficient reads become s_load (scalar pipe), leaving
// the inner loop as pure v_fmac_f32 (VGPR, SGPR, VGPR).
//
// Layout of cW:
//   [0..1199]    binom(9,k)*params[k, pairIdx], traversal order (i asc, j asc, k asc)
//   [1200..1215] lo[i]
//   [1216..1231] 1/(hi[i]-lo[i])

#define DVARS 16
#define KB 10
#define NPAIRS 120
#define NW (NPAIRS * KB)        // 1200
#define WTOT (NW + 2 * DVARS)   // 1232

__constant__ float cW[WTOT];

__global__ void decorr_prep(const float* __restrict__ params,
                            const float* __restrict__ poly_range,
                            float* __restrict__ W) {
    int t = blockIdx.x * blockDim.x + threadIdx.x;
    if (t < NW) {
        int k = t % KB;
        int pairIdx = t / KB;     // (i, j), i ascending, j in (i, 16)
        int i = 0, rem = pairIdx;
        while (rem >= (DVARS - 1) - i) { rem -= (DVARS - 1) - i; ++i; }
        int j = i + 1 + rem;
        int pidx = j * (j - 1) / 2 + i;   // reference PAIRS index (by var j, then covar i)
        const float BIN[KB] = {1.f, 9.f, 36.f, 84.f, 126.f, 126.f, 84.f, 36.f, 9.f, 1.f};
        W[t] = BIN[k] * params[k * NPAIRS + pidx];
    }
    if (t < DVARS) {
        float lo = poly_range[t];
        float hi = poly_range[DVARS + t];
        W[NW + t] = lo;
        W[NW + DVARS + t] = 1.0f / (hi - lo);
    }
}

__global__ __launch_bounds__(256) void decorr_main(const float* __restrict__ x,
                                                   float* __restrict__ out,
                                                   int nSamples) {
    int n = blockIdx.x * 256 + threadIdx.x;
    if (n >= nSamples) return;

    const float4* xr = reinterpret_cast<const float4*>(x + (size_t)n * DVARS);
    float4 a0 = xr[0], a1 = xr[1], a2 = xr[2], a3 = xr[3];
    float xv[DVARS] = {a0.x, a0.y, a0.z, a0.w,
                       a1.x, a1.y, a1.z, a1.w,
                       a2.x, a2.y, a2.z, a2.w,
                       a3.x, a3.y, a3.z, a3.w};

    float acc[DVARS];
#pragma unroll
    for (int j = 0; j < DVARS; ++j) acc[j] = xv[j];

    int pos = 0;
#pragma unroll
    for (int i = 0; i < DVARS - 1; ++i) {
        float u = (xv[i] - cW[NW + i]) * cW[NW + DVARS + i];
        float v = 1.0f - u;
        // u powers and (v powers * x_i) chain: t[k] = u^k * v^(9-k) * x_i
        float up[KB], vx[KB];
        up[0] = 1.0f;
        vx[0] = xv[i];
#pragma unroll
        for (int k = 1; k < KB; ++k) { up[k] = up[k - 1] * u; vx[k] = vx[k - 1] * v; }
        float t[KB];
#pragma unroll
        for (int k = 0; k < KB; ++k) t[k] = up[k] * vx[KB - 1 - k];  // up[0]*... folds
#pragma unroll
        for (int j = i + 1; j < DVARS; ++j) {
#pragma unroll
            for (int k = 0; k < KB; ++k) {
                acc[j] = fmaf(t[k], cW[pos + k], acc[j]);   // v_fmac with s_load'd coeff
            }
            pos += KB;
        }
    }

    float4* orow = reinterpret_cast<float4*>(out + (size_t)n * DVARS);
    orow[0] = make_float4(acc[0],  acc[1],  acc[2],  acc[3]);
    orow[1] = make_float4(acc[4],  acc[5],  acc[6],  acc[7]);
    orow[2] = make_float4(acc[8],  acc[9],  acc[10], acc[11]);
    orow[3] = make_float4(acc[12], acc[13], acc[14], acc[15]);
}

extern "C" void kernel_launch(void* const* d_in, const int* in_sizes, int n_in,
                              void* d_out, int out_size, void* d_ws, size_t ws_size,
                              hipStream_t stream) {
    const float* x      = (const float*)d_in[0];   // [N, 16]
    const float* params = (const float*)d_in[1];   // [10, 120]
    const float* prange = (const float*)d_in[2];   // [2, 16]
    float* out = (float*)d_out;
    float* W   = (float*)d_ws;                     // 1232 floats

    int nSamples = in_sizes[0] / DVARS;

    decorr_prep<<<(NW + 255) / 256, 256, 0, stream>>>(params, prange, W);

    void* sym = nullptr;
    hipGetSymbolAddress(&sym, HIP_SYMBOL(cW));     // pure query, capture-safe
    hipMemcpyAsync(sym, W, WTOT * sizeof(float), hipMemcpyDeviceToDevice, stream);

    decorr_main<<<(nSamples + 255) / 256, 256, 0, stream>>>(x, out, nSamples);
}

// Round 3
// 53.143 us; speedup vs baseline: 1.1650x; 1.1650x over previous
//
#include <hip/hip_runtime.h>
#include <hip/hip_bf16.h>

// Decorrelation forward, 2 samples/thread, packed fp32 (v_pk_fma_f32):
// out[n,j] = x[n,j] + sum_{i<j} sum_k Bin(9,k)*u_i^k*(1-u_i)^(9-k) * P[k,(i,j)] * x[n,i]
//
// Weight table (prep kernel -> d_ws -> __constant__):
//   float2 slots [0..1199]: {w, w} with w = binom(9,k)*params[k, pair(i,j)],
//                           traversal (i asc, j asc, k asc)  -> s_load_dwordx2
//   floats  [2400..2415]: lo[i]
//   floats  [2416..2431]: 1/(hi[i]-lo[i])

#define DVARS 16
#define KB 10
#define NPAIRS 120
#define NSLOT (NPAIRS * KB)          // 1200 float2 slots
#define WFLOATS (2 * NSLOT + 2 * DVARS)  // 2432 floats

typedef float v2f __attribute__((ext_vector_type(2)));

__constant__ float cW[WFLOATS];

__global__ void decorr_prep(const float* __restrict__ params,
                            const float* __restrict__ poly_range,
                            float* __restrict__ W) {
    int t = blockIdx.x * blockDim.x + threadIdx.x;
    if (t < NSLOT) {
        int k = t % KB;
        int pairIdx = t / KB;        // (i, j), i ascending, j in (i, 16)
        int i = 0, rem = pairIdx;
        while (rem >= (DVARS - 1) - i) { rem -= (DVARS - 1) - i; ++i; }
        int j = i + 1 + rem;
        int pidx = j * (j - 1) / 2 + i;   // reference PAIRS index (var j, covar i)
        const float BIN[KB] = {1.f, 9.f, 36.f, 84.f, 126.f, 126.f, 84.f, 36.f, 9.f, 1.f};
        float w = BIN[k] * params[k * NPAIRS + pidx];
        W[2 * t]     = w;
        W[2 * t + 1] = w;
    }
    if (t < DVARS) {
        float lo = poly_range[t];
        float hi = poly_range[DVARS + t];
        W[2 * NSLOT + t]         = lo;
        W[2 * NSLOT + DVARS + t] = 1.0f / (hi - lo);
    }
}

__global__ __launch_bounds__(256) void decorr_main(const float* __restrict__ x,
                                                   float* __restrict__ out,
                                                   int nSamples) {
    int half = (nSamples + 1) >> 1;
    int t0 = blockIdx.x * 256 + threadIdx.x;
    if (t0 >= half) return;
    int nA = t0;
    int nB = t0 + half;
    bool hasB = nB < nSamples;
    const float* xA = x + (size_t)nA * DVARS;
    const float* xB = x + (size_t)(hasB ? nB : nA) * DVARS;

    const float4* xrA = reinterpret_cast<const float4*>(xA);
    const float4* xrB = reinterpret_cast<const float4*>(xB);
    float4 a0 = xrA[0], a1 = xrA[1], a2 = xrA[2], a3 = xrA[3];
    float4 b0 = xrB[0], b1 = xrB[1], b2 = xrB[2], b3 = xrB[3];

    v2f xv[DVARS];
    xv[0]  = (v2f){a0.x, b0.x}; xv[1]  = (v2f){a0.y, b0.y};
    xv[2]  = (v2f){a0.z, b0.z}; xv[3]  = (v2f){a0.w, b0.w};
    xv[4]  = (v2f){a1.x, b1.x}; xv[5]  = (v2f){a1.y, b1.y};
    xv[6]  = (v2f){a1.z, b1.z}; xv[7]  = (v2f){a1.w, b1.w};
    xv[8]  = (v2f){a2.x, b2.x}; xv[9]  = (v2f){a2.y, b2.y};
    xv[10] = (v2f){a2.z, b2.z}; xv[11] = (v2f){a2.w, b2.w};
    xv[12] = (v2f){a3.x, b3.x}; xv[13] = (v2f){a3.y, b3.y};
    xv[14] = (v2f){a3.z, b3.z}; xv[15] = (v2f){a3.w, b3.w};

    v2f acc[DVARS];
#pragma unroll
    for (int j = 0; j < DVARS; ++j) acc[j] = xv[j];

    const v2f* __restrict__ W2 = reinterpret_cast<const v2f*>(cW);
    const float* __restrict__ Lo  = cW + 2 * NSLOT;
    const float* __restrict__ Inv = cW + 2 * NSLOT + DVARS;

    int pos = 0;
#pragma unroll
    for (int i = 0; i < DVARS - 1; ++i) {
        float lo = Lo[i], inv = Inv[i];
        v2f u = (xv[i] - (v2f){lo, lo}) * (v2f){inv, inv};
        v2f v = (v2f){1.0f, 1.0f} - u;
        // vx[k] = v^k * x_i ;  t[k] = u^k * v^(9-k) * x_i
        v2f vx[KB];
        vx[0] = xv[i];
#pragma unroll
        for (int k = 1; k < KB; ++k) vx[k] = vx[k - 1] * v;
        v2f t[KB];
        t[0] = vx[KB - 1];
        v2f run = u;
#pragma unroll
        for (int k = 1; k < KB; ++k) {
            t[k] = run * vx[KB - 1 - k];
            if (k < KB - 1) run = run * u;
        }
#pragma unroll
        for (int j = i + 1; j < DVARS; ++j) {
#pragma unroll
            for (int k = 0; k < KB; ++k) {
                acc[j] = __builtin_elementwise_fma(t[k], W2[pos + k], acc[j]);
            }
            pos += KB;
        }
    }

    float* oA = out + (size_t)nA * DVARS;
    float4* orA = reinterpret_cast<float4*>(oA);
    orA[0] = make_float4(acc[0].x,  acc[1].x,  acc[2].x,  acc[3].x);
    orA[1] = make_float4(acc[4].x,  acc[5].x,  acc[6].x,  acc[7].x);
    orA[2] = make_float4(acc[8].x,  acc[9].x,  acc[10].x, acc[11].x);
    orA[3] = make_float4(acc[12].x, acc[13].x, acc[14].x, acc[15].x);
    if (hasB) {
        float* oB = out + (size_t)nB * DVARS;
        float4* orB = reinterpret_cast<float4*>(oB);
        orB[0] = make_float4(acc[0].y,  acc[1].y,  acc[2].y,  acc[3].y);
        orB[1] = make_float4(acc[4].y,  acc[5].y,  acc[6].y,  acc[7].y);
        orB[2] = make_float4(acc[8].y,  acc[9].y,  acc[10].y, acc[11].y);
        orB[3] = make_float4(acc[12].y, acc[13].y, acc[14].y, acc[15].y);
    }
}

extern "C" void kernel_launch(void* const* d_in, const int* in_sizes, int n_in,
                              void* d_out, int out_size, void* d_ws, size_t ws_size,
                              hipStream_t stream) {
    const float* x      = (const float*)d_in[0];   // [N, 16]
    const float* params = (const float*)d_in[1];   // [10, 120]
    const float* prange = (const float*)d_in[2];   // [2, 16]
    float* out = (float*)d_out;
    float* W   = (float*)d_ws;                     // 2432 floats = 9728 B

    int nSamples = in_sizes[0] / DVARS;
    int half = (nSamples + 1) >> 1;

    decorr_prep<<<(NSLOT + 255) / 256, 256, 0, stream>>>(params, prange, W);

    void* sym = nullptr;
    hipGetSymbolAddress(&sym, HIP_SYMBOL(cW));
    hipMemcpyAsync(sym, W, WFLOATS * sizeof(float), hipMemcpyDeviceToDevice, stream);

    decorr_main<<<(half + 255) / 256, 256, 0, stream>>>(x, out, nSamples);
}

// Round 5
// 26.096 us; speedup vs baseline: 2.3724x; 2.0364x over previous
//
#include <hip/hip_runtime.h>
#include <hip/hip_bf16.h>

// Decorrelation as a tiny-GEMM: out[n,j] = x[n,j] + sum_k A[n,k]*B[k,j]
//   A[n, i*10+kk] = u_i^kk * (1-u_i)^(9-kk) * x[n,i]      (K = 160)
//   B[i*10+kk, j] = (i<j) ? binom(9,kk)*params[kk, pair(i,j)] : 0
// 5x v_mfma_f32_16x16x32_f16 per 16-sample tile, fp32 accumulate.
//
// B-fragments are precomputed per-lane by decorr_prep into d_ws and loaded
// ONCE per wave (20 VGPRs) -- no per-tile weight streaming at all.
// A-build and B-build use the SAME assumed (lane,element)->k map, so the
// contraction is correct for any consistent bijection; only the C/D layout
// (verified: col=lane&15, row=(lane>>4)*4+reg) must match hardware.

#define DVARS 16
#define KB 10
#define STEPS 5          // K=160 / 32
#define WPB 4            // waves per block (256 threads)

typedef _Float16 f16x8 __attribute__((ext_vector_type(8)));
typedef __fp16   h16x2 __attribute__((ext_vector_type(2)));
typedef float f32x4 __attribute__((ext_vector_type(4)));

static __device__ __forceinline__ unsigned packh2(float a, float b) {
    h16x2 h = __builtin_amdgcn_cvt_pkrtz(a, b);   // a -> low half, b -> high half
    unsigned r;
    __builtin_memcpy(&r, &h, 4);
    return r;
}

// ws layout: uint4 wsB[5*64] (5120 B) then float2 wsLI[16] (128 B)
__global__ void decorr_prep(const float* __restrict__ params,
                            const float* __restrict__ poly_range,
                            unsigned* __restrict__ wsB,
                            float2* __restrict__ wsLI) {
    int t = blockIdx.x * blockDim.x + threadIdx.x;
    if (t < STEPS * 64) {
        int s = t >> 6;
        int l = t & 63;
        int g = l >> 4;
        int n = l & 15;                 // output column j
        const float BIN[KB] = {1.f, 9.f, 36.f, 84.f, 126.f, 126.f, 84.f, 36.f, 9.f, 1.f};
        float w[8];
        for (int e = 0; e < 8; ++e) {
            int kg = 32 * s + 8 * g + e;   // same (lane,e)->k map as A-frag reads
            int i = kg / 10;
            int kk = kg % 10;
            float val = 0.f;
            if (i < n) val = BIN[kk] * params[kk * 120 + (n * (n - 1)) / 2 + i];
            w[e] = val;
        }
        for (int c = 0; c < 4; ++c)
            wsB[t * 4 + c] = packh2(w[2 * c], w[2 * c + 1]);
    }
    if (t < DVARS) {
        float lo = poly_range[t];
        float hi = poly_range[DVARS + t];
        wsLI[t] = make_float2(lo, 1.0f / (hi - lo));
    }
}

__global__ __launch_bounds__(256) void decorr_main(
        const float* __restrict__ x,
        const uint4* __restrict__ wsB,
        const float2* __restrict__ wsLI,
        float* __restrict__ out,
        int nSamples, int nTiles, int totalWaves)
{
    // per-wave private LDS regions (no cross-wave sync needed after startup)
    __shared__ __align__(16) unsigned As[WPB][16][84]; // packed f16 pairs; 160 halves + pad
    __shared__ __align__(16) float    Xs[WPB][16][20]; // x tile, padded pitch
    __shared__ float2 LI[DVARS];

    int tid = threadIdx.x;
    if (tid < DVARS) LI[tid] = wsLI[tid];
    __syncthreads();

    int lane = tid & 63;
    int wid  = tid >> 6;
    int g    = lane >> 4;
    int m15  = lane & 15;

    // B fragments: loaded once, live in VGPRs for the whole kernel
    f16x8 bfr[STEPS];
#pragma unroll
    for (int s = 0; s < STEPS; ++s) {
        uint4 raw = wsB[s * 64 + lane];
        __builtin_memcpy(&bfr[s], &raw, 16);
    }

    int tile = blockIdx.x * WPB + wid;
    if (tile >= nTiles) return;

    auto loadX = [&](int t_) -> float4 {
        int row = t_ * 16 + m15;
        if (row > nSamples - 1) row = nSamples - 1;
        return *reinterpret_cast<const float4*>(x + (size_t)row * DVARS + 4 * g);
    };

    float4 xv = loadX(tile);
    while (true) {
        int nextTile = tile + totalWaves;
        bool hasNext = nextTile < nTiles;               // wave-uniform
        float4 xvN = loadX(hasNext ? nextTile : tile);  // prefetch 1 tile ahead

        // ---- stage x tile into LDS (cross-lane -> explicit wait)
        *reinterpret_cast<float4*>(&Xs[wid][m15][4 * g]) = xv;
        asm volatile("s_waitcnt lgkmcnt(0)" ::: "memory");

        // ---- phase 1: Bernstein basis -> As (each lane: rows m15, i = g+4p)
#pragma unroll
        for (int p = 0; p < 4; ++p) {
            int i = g + 4 * p;
            float xm = Xs[wid][m15][i];
            float2 li = LI[i];
            float u = (xm - li.x) * li.y;
            float v = 1.0f - u;
            float vx[KB];
            vx[0] = xm;                                  // vx[k] = v^k * x_i
#pragma unroll
            for (int k = 1; k < KB; ++k) vx[k] = vx[k - 1] * v;
            float tk[KB];
            tk[0] = vx[KB - 1];
            float run = u;
#pragma unroll
            for (int k = 1; k < KB; ++k) {               // tk[k] = u^k v^(9-k) x_i
                tk[k] = run * vx[KB - 1 - k];
                if (k < KB - 1) run *= u;
            }
            unsigned* Arow = &As[wid][m15][0];
#pragma unroll
            for (int c = 0; c < 5; ++c)
                Arow[i * 5 + c] = packh2(tk[2 * c], tk[2 * c + 1]);
        }
        asm volatile("s_waitcnt lgkmcnt(0)" ::: "memory");

        // ---- phase 2: 5 MFMAs over K=160
        f32x4 acc = {0.f, 0.f, 0.f, 0.f};
        const unsigned* Arow = &As[wid][m15][0];
#pragma unroll
        for (int s = 0; s < STEPS; ++s) {
            f16x8 afr;
            __builtin_memcpy(&afr, Arow + 4 * g + 16 * s, 16);  // ds_read_b128
            acc = __builtin_amdgcn_mfma_f32_16x16x32_f16(afr, bfr[s], acc, 0, 0, 0);
        }

        // ---- epilogue: D[m,n]: n = lane&15, m = 4*(lane>>4)+r  (m89 C/D map)
        int base = tile * 16;
#pragma unroll
        for (int r = 0; r < 4; ++r) {
            int row = 4 * g + r;
            int sample = base + row;
            if (sample < nSamples)
                out[(size_t)sample * DVARS + m15] = acc[r] + Xs[wid][row][m15];
        }

        if (!hasNext) break;
        tile = nextTile;
        xv = xvN;
    }
}

extern "C" void kernel_launch(void* const* d_in, const int* in_sizes, int n_in,
                              void* d_out, int out_size, void* d_ws, size_t ws_size,
                              hipStream_t stream) {
    const float* x      = (const float*)d_in[0];   // [N, 16]
    const float* params = (const float*)d_in[1];   // [10, 120]
    const float* prange = (const float*)d_in[2];   // [2, 16]
    float* out = (float*)d_out;

    int nSamples = in_sizes[0] / DVARS;
    int nTiles = (nSamples + 15) / 16;

    unsigned* wsB = (unsigned*)d_ws;
    float2* wsLI  = (float2*)((char*)d_ws + STEPS * 64 * 16);

    decorr_prep<<<2, 256, 0, stream>>>(params, prange, wsB, wsLI);

    int blocks = 1280;                                // ~5 blocks/CU (LDS-capped)
    int maxBlocks = (nTiles + WPB - 1) / WPB;
    if (blocks > maxBlocks) blocks = maxBlocks;
    int totalWaves = blocks * WPB;

    decorr_main<<<blocks, 256, 0, stream>>>(x, (const uint4*)wsB, wsLI, out,
                                            nSamples, nTiles, totalWaves);
}

// Round 7
// 24.231 us; speedup vs baseline: 2.5551x; 1.0770x over previous
//
#include <hip/hip_runtime.h>
#include <hip/hip_bf16.h>

// Decorrelation as register-only tiny-GEMM per 16-sample tile:
//   out[n,j] = sum_k A[n,k]*B[k,j],  K=160
//   A[n, k(i,kk)] = u_i^kk * (1-u_i)^(9-kk) * x[n,i]        (NO binomial)
//   B[k(i,kk), j] = i<j  ? binom(9,kk)*params[kk, pair(i,j)]
//                 : i==j ? binom(9,kk)    <-- diagonal emits +x_j, since
//                          sum_kk binom(9,kk) u^kk v^(9-kk) = (u+v)^9 = 1
//                 : 0
//
// k-axis relabeled (valid: any global k-permutation applied to BOTH A and B
// leaves the contraction invariant; pairing assumption verified by R5) so
// that lane (m15,g)'s A-fragment = the 40 basis values it computes from its
// OWN contiguous float4 (row m15, cols 4g..4g+3). A is built entirely in
// registers: no LDS, no cross-lane ops, no barriers anywhere in the kernel.
//   lane-local flat index c in [0,40): i = 4g + c/10, kk = c%10
//   MFMA step s consumes halves c = 8s..8s+7.

#define DVARS 16
#define KB 10
#define STEPS 5          // K=160 / 32
#define WPB 4            // waves per block (256 threads)

typedef _Float16 f16x8 __attribute__((ext_vector_type(8)));
typedef __fp16   h16x2 __attribute__((ext_vector_type(2)));
typedef float    f32x4 __attribute__((ext_vector_type(4)));

static __device__ __forceinline__ unsigned packh2(float a, float b) {
    h16x2 h = __builtin_amdgcn_cvt_pkrtz(a, b);   // a -> low half, b -> high half
    unsigned r;
    __builtin_memcpy(&r, &h, 4);
    return r;
}

// ws layout: unsigned wsB[5*64*4] (5120 B) then float2 wsLI[16] (128 B)
__global__ void decorr_prep(const float* __restrict__ params,
                            const float* __restrict__ poly_range,
                            unsigned* __restrict__ wsB,
                            float2* __restrict__ wsLI) {
    int t = threadIdx.x;                  // single 512-thread block
    if (t < STEPS * 64) {
        int s = t >> 6;
        int l = t & 63;
        int g = l >> 4;
        int n = l & 15;                   // output column j
        const float BIN[KB] = {1.f, 9.f, 36.f, 84.f, 126.f, 126.f, 84.f, 36.f, 9.f, 1.f};
        float w[8];
        for (int e = 0; e < 8; ++e) {
            int c = 8 * s + e;            // lane-local flat index, 0..39
            int i = 4 * g + c / 10;
            int kk = c % 10;
            float val = 0.f;
            if (i < n)       val = BIN[kk] * params[kk * 120 + (n * (n - 1)) / 2 + i];
            else if (i == n) val = BIN[kk];  // diagonal: sum_kk BIN*u^k*v^(9-k) = 1 -> +x_j
            w[e] = val;
        }
        for (int cc = 0; cc < 4; ++cc)
            wsB[t * 4 + cc] = packh2(w[2 * cc], w[2 * cc + 1]);
    }
    if (t < DVARS) {
        float lo = poly_range[t];
        float hi = poly_range[DVARS + t];
        wsLI[t] = make_float2(lo, 1.0f / (hi - lo));
    }
}

__global__ __launch_bounds__(256) void decorr_main(
        const float* __restrict__ x,
        const uint4* __restrict__ wsB,
        const float2* __restrict__ wsLI,
        float* __restrict__ out,
        int nSamples, int nTiles, int totalWaves)
{
    int tid  = threadIdx.x;
    int lane = tid & 63;
    int wid  = tid >> 6;
    int g    = lane >> 4;
    int m15  = lane & 15;

    // B fragments: loaded once per wave, live in VGPRs for the whole kernel
    f16x8 bfr[STEPS];
#pragma unroll
    for (int s = 0; s < STEPS; ++s) {
        uint4 raw = wsB[s * 64 + lane];
        __builtin_memcpy(&bfr[s], &raw, 16);
    }
    // normalization constants for this lane's 4 covariate columns i = 4g+q
    float2 li[4];
#pragma unroll
    for (int q = 0; q < 4; ++q) li[q] = wsLI[4 * g + q];

    int tile = blockIdx.x * WPB + wid;
    if (tile >= nTiles) return;

    auto loadX = [&](int t_) -> float4 {
        int row = t_ * 16 + m15;
        if (row > nSamples - 1) row = nSamples - 1;
        return *reinterpret_cast<const float4*>(x + (size_t)row * DVARS + 4 * g);
    };

    float4 xv = loadX(tile);
    while (true) {
        int nextTile = tile + totalWaves;
        bool hasNext = nextTile < nTiles;               // wave-uniform
        float4 xvN = loadX(hasNext ? nextTile : tile);  // prefetch 1 tile ahead

        // ---- build A-fragment in registers: i = 4g+q from own float4 lanes
        unsigned afr[STEPS * 4];                        // 20 dwords = 40 halves
        const float* xl = reinterpret_cast<const float*>(&xv);
#pragma unroll
        for (int q = 0; q < 4; ++q) {
            float xm = xl[q];
            float u = (xm - li[q].x) * li[q].y;
            float v = 1.0f - u;
            float vx[KB];
            vx[0] = xm;                                  // vx[k] = v^k * x_i
#pragma unroll
            for (int k = 1; k < KB; ++k) vx[k] = vx[k - 1] * v;
            float tk[KB];
            tk[0] = vx[KB - 1];
            float run = u;
#pragma unroll
            for (int k = 1; k < KB; ++k) {               // tk[k] = u^k v^(9-k) x_i
                tk[k] = run * vx[KB - 1 - k];
                if (k < KB - 1) run *= u;
            }
#pragma unroll
            for (int h = 0; h < 5; ++h)                  // flat half idx c = 10q+2h(+1)
                afr[5 * q + h] = packh2(tk[2 * h], tk[2 * h + 1]);
        }

        // ---- 5 MFMAs over K=160, all operands in registers
        f32x4 acc = {0.f, 0.f, 0.f, 0.f};
#pragma unroll
        for (int s = 0; s < STEPS; ++s) {
            f16x8 a;
            __builtin_memcpy(&a, &afr[4 * s], 16);
            acc = __builtin_amdgcn_mfma_f32_16x16x32_f16(a, bfr[s], acc, 0, 0, 0);
        }

        // ---- store: D col = lane&15, row = 4*(lane>>4)+r (verified C/D map)
        int base = tile * 16;
#pragma unroll
        for (int r = 0; r < 4; ++r) {
            int sample = base + 4 * g + r;
            if (sample < nSamples)
                out[(size_t)sample * DVARS + m15] = acc[r];
        }

        if (!hasNext) break;
        tile = nextTile;
        xv = xvN;
    }
}

extern "C" void kernel_launch(void* const* d_in, const int* in_sizes, int n_in,
                              void* d_out, int out_size, void* d_ws, size_t ws_size,
                              hipStream_t stream) {
    const float* x      = (const float*)d_in[0];   // [N, 16]
    const float* params = (const float*)d_in[1];   // [10, 120]
    const float* prange = (const float*)d_in[2];   // [2, 16]
    float* out = (float*)d_out;

    int nSamples = in_sizes[0] / DVARS;
    int nTiles = (nSamples + 15) / 16;

    unsigned* wsB = (unsigned*)d_ws;
    float2* wsLI  = (float2*)((char*)d_ws + STEPS * 64 * 16);

    decorr_prep<<<1, 512, 0, stream>>>(params, prange, wsB, wsLI);

    int blocks = 2048;                              // memory-bound grid cap
    int maxBlocks = (nTiles + WPB - 1) / WPB;
    if (blocks > maxBlocks) blocks = maxBlocks;
    int totalWaves = blocks * WPB;

    decorr_main<<<blocks, 256, 0, stream>>>(x, (const uint4*)wsB, wsLI, out,
                                            nSamples, nTiles, totalWaves);
}